// Round 5
// baseline (134.142 us; speedup 1.0000x reference)
//
#include <hip/hip_runtime.h>

// CharGRU2: 2-layer GRU (reset_after=true) + dense + softmax, fp32.
// B=2048, T=128, V=256, H=20, L=15.
//
// Round 17 = R16 (exp2 pre-scaled gates, parallel DPP hops, rec1 dot mid-
// iteration, LDS h-broadcast, pk_fma dots) x TWO BATCHES PER WAVE:
//
//  Measured R16: VALUBusy 58%, wall ~1050 cy/iter, per-SIMD issue ~610 cy.
//  Two co-resident waves run identical schedules and stall in the same
//  neighborhoods (lgkmcnt + trans chains) — wave-level TLP never fills the
//  ~440 idle cy. Fix: 1 wave/SIMD, each wave interleaving two INDEPENDENT
//  batch streams at instruction level. Weight VGPRs (60) are shared by both
//  streams; only state/quads duplicate (+~50 VGPR). Per-SIMD issue load is
//  unchanged; every stall in stream A has stream B's independent work
//  adjacent in program order.
//
// Grid: 256 blocks x 256 threads = 1 block/CU; wave w handles batches
// blockIdx*8 + 2w and +2w+1.
//
// Layout recap: lane 16r+3u+p owns gate column p*20+(5r+u) (p=0:z 1:r 2:h~);
// home lane of unit j = 16*(j/5)+3*(j%5)+2; lane 16r+15 dups pos 14 and is
// excluded from LDS writes. Gate hops never cross a 16-lane DPP row.

#define BB 2048
#define TT 128
#define HH 20
#define LL 15
#define H3 60

typedef float v2f __attribute__((ext_vector_type(2)));

#if __has_builtin(__builtin_amdgcn_exp2f)
#define EXP2(x) __builtin_amdgcn_exp2f(x)
#else
#define EXP2(x) exp2f(x)
#endif

__device__ __forceinline__ float bclane(float v, int k) {
    return __int_as_float(__builtin_amdgcn_readlane(__float_as_int(v), k));
}
__device__ __forceinline__ float dpp_rshr1(float v) {
    return __int_as_float(__builtin_amdgcn_update_dpp(
        0, __float_as_int(v), 0x111, 0xF, 0xF, true));
}
__device__ __forceinline__ float dpp_rshr2(float v) {
    return __int_as_float(__builtin_amdgcn_update_dpp(
        0, __float_as_int(v), 0x112, 0xF, 0xF, true));
}
__device__ __forceinline__ float fast_rcp(float x) { return __builtin_amdgcn_rcpf(x); }
#define PIN(v) asm volatile("" : "+v"(v))
#define LDSFENCE() asm volatile("" ::: "memory")

extern "C" __global__ __launch_bounds__(256)
__attribute__((amdgpu_waves_per_eu(1, 1)))
void gru2_kernel(const int* __restrict__ x, const float* __restrict__ W0,
                 const float* __restrict__ U0, const float* __restrict__ b0i,
                 const float* __restrict__ b0r, const float* __restrict__ W1,
                 const float* __restrict__ U1, const float* __restrict__ b1i,
                 const float* __restrict__ b1r, const float* __restrict__ Wd,
                 const float* __restrict__ bd, float* __restrict__ out)
{
    const int lane = threadIdx.x & 63;
    const int w = threadIdx.x >> 6;
    const int row = lane >> 4;                           // DPP row 0..3
    const int pos = lane & 15;                           // pos in row
    const int pc  = (pos < 15) ? pos : 14;               // lane 16r+15 dups pos 14
    const int u   = pc / 3;                              // unit-in-row 0..4
    const int p3  = pc % 3;                              // 0:z 1:r 2:h~
    const int j   = row * 5 + u;                         // unit 0..19
    const bool home = (pos < 15) && (p3 == 2);           // 20 h-home lanes
    const int col = p3 * 20 + j;                         // owned gate column

    // exp2 gate scale: z/r columns -log2e, h~ columns -2log2e
    const float gsc = (p3 == 2) ? -2.8853900817779268f : -1.4426950408889634f;

    // per-wave, per-batch LDS staging of h0/h1 (wave-uniform broadcasts)
    __shared__ __align__(16) float hbuf[4][2][2][24];    // [wave][batch][layer][]
    float* hA0 = &hbuf[w][0][0][0];
    float* hA1 = &hbuf[w][0][1][0];
    float* hB0 = &hbuf[w][1][0][0];
    float* hB1 = &hbuf[w][1][1][0];
    const float4* qA0 = (const float4*)hA0;
    const float4* qA1 = (const float4*)hA1;
    const float4* qB0 = (const float4*)hB0;
    const float4* qB1 = (const float4*)hB1;
    if (home) { hA0[j] = 0.f; hA1[j] = 0.f; hB0[j] = 0.f; hB1[j] = 0.f; }
    LDSFENCE();

    // ---- weight columns (k-pair packed, pre-scaled), SHARED by both batches
    v2f u0p[10], w1p[10], u1p[10];
#pragma unroll
    for (int q = 0; q < 10; ++q) {
        const int k0 = (2 * q) * H3, k1 = (2 * q + 1) * H3;
        u0p[q] = v2f{U0[k0 + col] * gsc, U0[k1 + col] * gsc};
        w1p[q] = v2f{W1[k0 + col] * gsc, W1[k1 + col] * gsc};
        u1p[q] = v2f{U1[k0 + col] * gsc, U1[k1 + col] * gsc};
    }
#pragma unroll
    for (int q = 0; q < 10; ++q) { PIN(u0p[q]); PIN(w1p[q]); PIN(u1p[q]); }
    float bi0 = b0i[col] * gsc, br0 = b0r[col] * gsc;
    float bi1 = b1i[col] * gsc, br1 = b1r[col] * gsc;
    PIN(bi0); PIN(br0); PIN(bi1); PIN(br1);

    // ---- tokens: batch A = blockIdx*8 + 2w, batch B = A+1 ----
    const int bA = blockIdx.x * 8 + w * 2;
    const int* xrA = x + bA * TT;
    const int* xrB = xrA + TT;
    const int tAlo = xrA[lane], tAhi = xrA[64 + lane];
    const int tBlo = xrB[lane], tBhi = xrB[64 + lane];

    float h0A = 0.f, h1A = 0.f, h0B = 0.f, h1B = 0.f;

    // ---- W0 pipelines (per batch): row t ready(scaled), t+1 raw, tok t+2 ----
    int toknA = __builtin_amdgcn_readlane(tAlo, 2);
    int toknB = __builtin_amdgcn_readlane(tBlo, 2);
    float xwAc = fmaf(W0[__builtin_amdgcn_readlane(tAlo, 0) * H3 + col], gsc, bi0);
    float xwAn = W0[__builtin_amdgcn_readlane(tAlo, 1) * H3 + col];
    float xwBc = fmaf(W0[__builtin_amdgcn_readlane(tBlo, 0) * H3 + col], gsc, bi0);
    float xwBn = W0[__builtin_amdgcn_readlane(tBlo, 1) * H3 + col];

    float4 cA0[5], cA1[5], cB0[5], cB1[5];               // register-staged quads
    float recA0, xwA1, recA1, recB0, xwB1, recB1;

    // dots from C (=h0_t): rec0 (U0) + xw1 (W1)
#define DOT01(C, R0, X1)                                                      \
    {                                                                         \
        v2f a0a = v2f{br0, 0.f}, a0b = v2f{0.f, 0.f};                         \
        v2f a1a = v2f{bi1, 0.f}, a1b = v2f{0.f, 0.f};                         \
        _Pragma("unroll")                                                     \
        for (int q = 0; q < 5; ++q) {                                         \
            const v2f hA_ = v2f{C[q].x, C[q].y}, hB_ = v2f{C[q].z, C[q].w};   \
            a0a = __builtin_elementwise_fma(hA_, u0p[2 * q], a0a);            \
            a0b = __builtin_elementwise_fma(hB_, u0p[2 * q + 1], a0b);        \
            a1a = __builtin_elementwise_fma(hA_, w1p[2 * q], a1a);            \
            a1b = __builtin_elementwise_fma(hB_, w1p[2 * q + 1], a1b);        \
        }                                                                     \
        { const v2f t_ = a0a + a0b; R0 = t_.x + t_.y; }                       \
        { const v2f t_ = a1a + a1b; X1 = t_.x + t_.y; }                       \
    }
    // dot from C (=h1_{t-1}): rec1 (U1)
#define DOT2(C, R1)                                                           \
    {                                                                         \
        v2f a2a = v2f{br1, 0.f}, a2b = v2f{0.f, 0.f};                         \
        _Pragma("unroll")                                                     \
        for (int q = 0; q < 5; ++q) {                                         \
            const v2f gA_ = v2f{C[q].x, C[q].y}, gB_ = v2f{C[q].z, C[q].w};   \
            a2a = __builtin_elementwise_fma(gA_, u1p[2 * q], a2a);            \
            a2b = __builtin_elementwise_fma(gB_, u1p[2 * q + 1], a2b);        \
        }                                                                     \
        { const v2f t_ = a2a + a2b; R1 = t_.x + t_.y; }                       \
    }
    // gate block: one exp2/rcp stream serves z,r (sigmoid) and h~ (tanh)
#define GATES(XW, REC, H)                                                     \
    {                                                                         \
        const float e_  = EXP2((XW) + (REC));                                 \
        const float t_  = fast_rcp(1.f + e_);                                 \
        const float rv_ = dpp_rshr1(t_);                                      \
        const float zv_ = dpp_rshr2(t_);                                      \
        const float eh_ = EXP2(fmaf(rv_, (REC), (XW)));                       \
        const float th_ = fast_rcp(1.f + eh_);                                \
        const float hh_ = fmaf(2.f, th_, -1.f);                               \
        H = fmaf(zv_, (H) - hh_, hh_);                                        \
    }

    // ---- prologue: L0 for t=0 both batches (rec0 = br0); c*1 = zeros ----
    {
        const float pfA = W0[toknA * H3 + col];
        const float pfB = W0[toknB * H3 + col];
        const int tA3 = __builtin_amdgcn_readlane(tAlo, 3);
        const int tB3 = __builtin_amdgcn_readlane(tBlo, 3);
        GATES(xwAc, br0, h0A);
        GATES(xwBc, br0, h0B);
        if (home) { hA0[j] = h0A; hB0[j] = h0B; }
        LDSFENCE();
#pragma unroll
        for (int q = 0; q < 5; ++q) {
            cA0[q] = qA0[q]; cA1[q] = qA1[q];
            cB0[q] = qB0[q]; cB1[q] = qB1[q];
        }
        xwAc = fmaf(xwAn, gsc, bi0); xwAn = pfA; toknA = tA3;
        xwBc = fmaf(xwBn, gsc, bi0); xwBn = pfB; toknB = tB3;
        DOT01(cA0, recA0, xwA1);
        DOT01(cB0, recB0, xwB1);
    }

    // ---- main loop: i = 1..127 ----
#pragma unroll 2
    for (int i = 1; i < TT; ++i) {
        const int t3 = (i + 3 < TT) ? (i + 3) : (TT - 1);
        const float pfA = W0[toknA * H3 + col];
        const float pfB = W0[toknB * H3 + col];
        const int tA3 = __builtin_amdgcn_readlane(t3 < 64 ? tAlo : tAhi, t3 & 63);
        const int tB3 = __builtin_amdgcn_readlane(t3 < 64 ? tBlo : tBhi, t3 & 63);

        // ---- L0 gates (t=i), both streams interleave ----
        GATES(xwAc, recA0, h0A);
        GATES(xwBc, recB0, h0B);
        if (home) { hA0[j] = h0A; hB0[j] = h0B; }
        LDSFENCE();
#pragma unroll
        for (int q = 0; q < 5; ++q) { cA0[q] = qA0[q]; cB0[q] = qB0[q]; }

        // ---- rec1 dots: c*1 read one full iteration ago ----
        DOT2(cA1, recA1);
        DOT2(cB1, recB1);

        // ---- L1 gates (t=i-1) ----
        GATES(xwA1, recA1, h1A);
        GATES(xwB1, recB1, h1B);
        if (home) { hA1[j] = h1A; hB1[j] = h1B; }
        LDSFENCE();
#pragma unroll
        for (int q = 0; q < 5; ++q) { cA1[q] = qA1[q]; cB1[q] = qB1[q]; }

        // rotate W0 pipelines
        xwAc = fmaf(xwAn, gsc, bi0); xwAn = pfA; toknA = tA3;
        xwBc = fmaf(xwBn, gsc, bi0); xwBn = pfB; toknB = tB3;

        // ---- tail dots for i+1 ----
        DOT01(cA0, recA0, xwA1);
        DOT01(cB0, recB0, xwB1);
    }

    // ---- epilogue: L1 for t=127, both batches ----
    {
        DOT2(cA1, recA1);
        DOT2(cB1, recB1);
        GATES(xwA1, recA1, h1A);
        GATES(xwB1, recB1, h1B);
        if (home) { hA1[j] = h1A; hB1[j] = h1B; }
        LDSFENCE();
    }

    // ---- dense (h1 @ Wd + bd) + softmax, per batch ----
    const int l = lane < LL ? lane : LL - 1;
    float accA = bd[l], accB = accA;
#pragma unroll
    for (int k = 0; k < HH; ++k) {
        const float wd = Wd[k * LL + l];
        accA = fmaf(hA1[k], wd, accA);
        accB = fmaf(hB1[k], wd, accB);
    }

    float mA = accA, mB = accB;
#pragma unroll
    for (int i = 0; i < LL; ++i) {
        mA = fmaxf(mA, bclane(accA, i));
        mB = fmaxf(mB, bclane(accB, i));
    }
    const float eA = __expf(accA - mA);
    const float eB = __expf(accB - mB);
    float sA = 0.f, sB = 0.f;
#pragma unroll
    for (int i = 0; i < LL; ++i) {
        sA += bclane(eA, i);
        sB += bclane(eB, i);
    }
    const float prA = eA * fast_rcp(sA);
    const float prB = eB * fast_rcp(sB);

    if (lane < LL) {
        out[bA * LL + lane] = prA;
        out[(bA + 1) * LL + lane] = prB;
    }
}

extern "C" void kernel_launch(void* const* d_in, const int* in_sizes, int n_in,
                              void* d_out, int out_size, void* d_ws, size_t ws_size,
                              hipStream_t stream) {
    const int*   x   = (const int*)  d_in[0];
    const float* W0  = (const float*)d_in[1];
    const float* U0  = (const float*)d_in[2];
    const float* b0i = (const float*)d_in[3];
    const float* b0r = (const float*)d_in[4];
    const float* W1  = (const float*)d_in[5];
    const float* U1  = (const float*)d_in[6];
    const float* b1i = (const float*)d_in[7];
    const float* b1r = (const float*)d_in[8];
    const float* Wd  = (const float*)d_in[9];
    const float* bd  = (const float*)d_in[10];
    // d_in[11] = drop_rate (identity), unused
    float* out = (float*)d_out;

    // 2 batches/wave, 4 waves/block -> 256 blocks = 1 block/CU = 1 wave/SIMD.
    dim3 grid(BB / 8), block(256);
    hipLaunchKernelGGL(gru2_kernel, grid, block, 0, stream,
                       x, W0, U0, b0i, b0r, W1, U1, b1i, b1r, Wd, bd, out);
}